// Round 1
// baseline (2923.894 us; speedup 1.0000x reference)
//
#include <hip/hip_runtime.h>
#include <hip/hip_bf16.h>

#define NN0 200000
#define NN1 50000
#define NN2 10000
#define E0C 800000
#define E1C 160000
#define IN_DIM 512
#define HD 256
#define OUT_D 128

typedef unsigned short u16;
typedef unsigned int u32;

__device__ __forceinline__ float b2f(u16 u){ return __uint_as_float(((u32)u)<<16); }
__device__ __forceinline__ u16 f2b(float f){
  u32 x = __float_as_uint(f);
  u32 r = x + 0x7fffu + ((x>>16)&1u);
  return (u16)(r>>16);
}

// ---- degree counting (int atomics) ----
__global__ void deg_count(const int* __restrict__ src, const int* __restrict__ dst,
                          int E, int* __restrict__ outc, int* __restrict__ inc){
  int i = blockIdx.x*blockDim.x + threadIdx.x;
  if (i < E){
    atomicAdd(&outc[src[i]], 1);
    atomicAdd(&inc[dst[i]], 1);
  }
}

__global__ void mkscale(const int* __restrict__ c, float* __restrict__ o, int n){
  int i = blockIdx.x*blockDim.x + threadIdx.x;
  if (i < n) o[i] = rsqrtf((float)(c[i] > 1 ? c[i] : 1));
}

// ---- exclusive scan (single block, shuffle-based) ----
__global__ __launch_bounds__(1024) void scan_kernel(const int* __restrict__ cnt,
    int* __restrict__ off, int* __restrict__ cur, int n){
  __shared__ int wsum[16];
  int tid = threadIdx.x, lane = tid & 63, wv = tid >> 6;
  int carry = 0;
  for (int base = 0; base < n; base += 1024){
    int i = base + tid;
    int v = (i < n) ? cnt[i] : 0;
    int x = v;
    #pragma unroll
    for (int d = 1; d < 64; d <<= 1){
      int y = __shfl_up(x, d);
      if (lane >= d) x += y;
    }
    if (lane == 63) wsum[wv] = x;
    __syncthreads();
    if (tid == 0){
      int s = carry;
      #pragma unroll
      for (int k = 0; k < 16; ++k){ int t = wsum[k]; wsum[k] = s; s += t; }
      carry = s;
    }
    __syncthreads();
    int excl = wsum[wv] + x - v;
    if (i < n){ off[i] = excl; cur[i] = excl; }
    __syncthreads();
  }
  if (tid == 0) off[n] = carry;
}

__global__ void fill_kernel(const int* __restrict__ src, const int* __restrict__ dst,
                            int E, int* __restrict__ cur, int* __restrict__ lst){
  int i = blockIdx.x*blockDim.x + threadIdx.x;
  if (i < E){
    int d = dst[i];
    int p = atomicAdd(&cur[d], 1);
    lst[p] = src[i];
  }
}

// ---- fp32 GEMM: C[M,N] = A[M,K] @ W[K,N] + bias, thread-per-column ----
// A fp32 or bf16; C fp32 or bf16; optional ReLU. BM=32 rows/block, BK=64.
template<int N, int K, bool RELU, bool ABF, bool OBF>
__global__ __launch_bounds__(N, 2) void gemm_tpc(const void* __restrict__ Av,
    const float* __restrict__ W, const float* __restrict__ bias,
    void* __restrict__ Cv, int M)
{
  constexpr int BM = 32, BK = 64, LDA = BK + 4;
  __shared__ float at[BM * LDA];
  const int t = threadIdx.x;
  const int r0 = blockIdx.x * BM;
  float acc[BM];
  #pragma unroll
  for (int r = 0; r < BM; ++r) acc[r] = 0.f;

  for (int k0 = 0; k0 < K; k0 += BK){
    constexpr int PER = (BM*BK)/N;
    #pragma unroll
    for (int j = 0; j < PER; ++j){
      int idx = j*N + t;
      int r = idx >> 6, kk = idx & 63;
      int gr = r0 + r;
      float v = 0.f;
      if (gr < M){
        if (ABF) v = b2f(((const u16*)Av)[(size_t)gr*K + k0 + kk]);
        else     v = ((const float*)Av)[(size_t)gr*K + k0 + kk];
      }
      at[r*LDA + kk] = v;
    }
    __syncthreads();
    float w[BK];
    #pragma unroll
    for (int kk = 0; kk < BK; ++kk) w[kk] = W[(size_t)(k0+kk)*N + t];
    #pragma unroll
    for (int r = 0; r < BM; ++r){
      const float* ar = &at[r*LDA];
      float s = acc[r];
      #pragma unroll
      for (int kk = 0; kk < BK; kk += 4){
        float4 a4 = *(const float4*)(ar + kk);
        s = fmaf(a4.x, w[kk+0], s);
        s = fmaf(a4.y, w[kk+1], s);
        s = fmaf(a4.z, w[kk+2], s);
        s = fmaf(a4.w, w[kk+3], s);
      }
      acc[r] = s;
    }
    __syncthreads();
  }
  float b = bias[t];
  #pragma unroll
  for (int r = 0; r < BM; ++r){
    int gr = r0 + r;
    if (gr < M){
      float v = acc[r] + b;
      if (RELU) v = fmaxf(v, 0.f);
      if (OBF) ((u16*)Cv)[(size_t)gr*N + t] = f2b(v);
      else     ((float*)Cv)[(size_t)gr*N + t] = v;
    }
  }
}

// ---- CSR pull aggregation: out[d] = rs_in[d] * sum_e so[src_e]*X[src_e], 256-dim bf16 ----
__global__ __launch_bounds__(256) void agg_kernel(const u16* __restrict__ X,
    const int* __restrict__ off, const int* __restrict__ lst,
    const float* __restrict__ so, const float* __restrict__ ri,
    u16* __restrict__ out, int nd)
{
  int lane = threadIdx.x & 63, wv = threadIdx.x >> 6;
  int d = blockIdx.x*4 + wv;
  if (d >= nd) return;
  int e0 = off[d], e1 = off[d+1];
  float a0=0.f, a1=0.f, a2=0.f, a3=0.f;
  for (int e = e0; e < e1; ++e){
    int s = lst[e];
    float sc = so[s];
    ushort4 u = ((const ushort4*)X)[(size_t)s*64 + lane];
    a0 = fmaf(b2f(u.x), sc, a0);
    a1 = fmaf(b2f(u.y), sc, a1);
    a2 = fmaf(b2f(u.z), sc, a2);
    a3 = fmaf(b2f(u.w), sc, a3);
  }
  float r = ri[d];
  ushort4 o;
  o.x = f2b(a0*r); o.y = f2b(a1*r); o.z = f2b(a2*r); o.w = f2b(a3*r);
  ((ushort4*)out)[(size_t)d*64 + lane] = o;
}

// ---- LayerNorm over 256 cols, in-place bf16, one wave per row ----
__global__ __launch_bounds__(256) void ln_kernel(u16* __restrict__ H,
    const float* __restrict__ g, const float* __restrict__ b, int n)
{
  int lane = threadIdx.x & 63, wv = threadIdx.x >> 6;
  int r = blockIdx.x*4 + wv;
  if (r >= n) return;
  ushort4 u = ((const ushort4*)H)[(size_t)r*64 + lane];
  float x0=b2f(u.x), x1=b2f(u.y), x2=b2f(u.z), x3=b2f(u.w);
  float s = x0+x1+x2+x3;
  #pragma unroll
  for (int d=1; d<64; d<<=1) s += __shfl_xor(s, d);
  float mu = s * (1.f/256.f);
  float d0=x0-mu, d1=x1-mu, d2=x2-mu, d3=x3-mu;
  float v = d0*d0 + d1*d1 + d2*d2 + d3*d3;
  #pragma unroll
  for (int d=1; d<64; d<<=1) v += __shfl_xor(v, d);
  float inv = rsqrtf(v*(1.f/256.f) + 1e-5f);
  float4 gv = ((const float4*)g)[lane];
  float4 bv = ((const float4*)b)[lane];
  ushort4 o;
  o.x = f2b(d0*inv*gv.x + bv.x);
  o.y = f2b(d1*inv*gv.y + bv.y);
  o.z = f2b(d2*inv*gv.z + bv.z);
  o.w = f2b(d3*inv*gv.w + bv.w);
  ((ushort4*)H)[(size_t)r*64 + lane] = o;
}

// ---- row L2-normalize, 128 cols, one wave per row ----
__global__ __launch_bounds__(256) void rownorm_kernel(const float* __restrict__ T,
    float* __restrict__ out, int n)
{
  int lane = threadIdx.x & 63, wv = threadIdx.x >> 6;
  int r = blockIdx.x*4 + wv;
  if (r >= n) return;
  float2 x = ((const float2*)T)[(size_t)r*64 + lane];
  float s = x.x*x.x + x.y*x.y;
  #pragma unroll
  for (int d=1; d<64; d<<=1) s += __shfl_xor(s, d);
  float nrm = sqrtf(s);
  float sc = 1.f / fmaxf(nrm, 1e-12f);
  float2 o; o.x = x.x*sc; o.y = x.y*sc;
  ((float2*)out)[(size_t)r*64 + lane] = o;
}

extern "C" void kernel_launch(void* const* d_in, const int* in_sizes, int n_in,
                              void* d_out, int out_size, void* d_ws, size_t ws_size,
                              hipStream_t stream)
{
  const float* feats = (const float*)d_in[0];
  const int*   b0s   = (const int*)d_in[1];
  const int*   b0d   = (const int*)d_in[2];
  const int*   b1s   = (const int*)d_in[3];
  const int*   b1d   = (const int*)d_in[4];
  const float* W1    = (const float*)d_in[5];
  const float* bias1 = (const float*)d_in[6];
  const float* Wc    = (const float*)d_in[7];
  const float* bc    = (const float*)d_in[8];
  const float* lng   = (const float*)d_in[9];
  const float* lnb   = (const float*)d_in[10];
  const float* Wo    = (const float*)d_in[11];
  const float* bo    = (const float*)d_in[12];
  const int E0 = in_sizes[1];
  const int E1 = in_sizes[3];
  (void)n_in; (void)out_size; (void)ws_size;

  char* p = (char*)d_ws;
  auto alloc = [&](size_t bytes)->void*{ void* q = (void*)p; p += (bytes + 255) & ~(size_t)255; return q; };
  u16*   h    = (u16*)  alloc((size_t)NN0*HD*2);     // i2h output, bf16
  u16*   hb   = (u16*)  alloc((size_t)NN1*HD*2);     // agg1 / conv1-out / LN, in-place chain
  u16*   ag2  = (u16*)  alloc((size_t)NN2*HD*2);
  float* c2   = (float*)alloc((size_t)NN2*OUT_D*4);
  char* cnt_begin = p;
  int* outc0 = (int*)alloc((size_t)NN0*4);
  int* inc0  = (int*)alloc((size_t)NN1*4);
  int* outc1 = (int*)alloc((size_t)NN1*4);
  int* inc1  = (int*)alloc((size_t)NN2*4);
  char* cnt_end = p;
  float* so0 = (float*)alloc((size_t)NN0*4);
  float* ri0 = (float*)alloc((size_t)NN1*4);
  float* so1 = (float*)alloc((size_t)NN1*4);
  float* ri1 = (float*)alloc((size_t)NN2*4);
  int* off0  = (int*)alloc((size_t)(NN1+1)*4);
  int* cur0  = (int*)alloc((size_t)NN1*4);
  int* off1  = (int*)alloc((size_t)(NN2+1)*4);
  int* cur1  = (int*)alloc((size_t)NN2*4);
  int* lst0  = (int*)alloc((size_t)E0C*4);
  int* lst1  = (int*)alloc((size_t)E1C*4);

  hipMemsetAsync(cnt_begin, 0, (size_t)(cnt_end - cnt_begin), stream);

  deg_count<<<(E0+255)/256, 256, 0, stream>>>(b0s, b0d, E0, outc0, inc0);
  deg_count<<<(E1+255)/256, 256, 0, stream>>>(b1s, b1d, E1, outc1, inc1);
  mkscale<<<(NN0+255)/256, 256, 0, stream>>>(outc0, so0, NN0);
  mkscale<<<(NN1+255)/256, 256, 0, stream>>>(inc0,  ri0, NN1);
  mkscale<<<(NN1+255)/256, 256, 0, stream>>>(outc1, so1, NN1);
  mkscale<<<(NN2+255)/256, 256, 0, stream>>>(inc1,  ri1, NN2);
  scan_kernel<<<1, 1024, 0, stream>>>(inc0, off0, cur0, NN1);
  scan_kernel<<<1, 1024, 0, stream>>>(inc1, off1, cur1, NN2);
  fill_kernel<<<(E0+255)/256, 256, 0, stream>>>(b0s, b0d, E0, cur0, lst0);
  fill_kernel<<<(E1+255)/256, 256, 0, stream>>>(b1s, b1d, E1, cur1, lst1);

  // h = feats @ W1 + bias1                      [200000,512]@[512,256]
  gemm_tpc<HD, IN_DIM, false, false, true><<<(NN0+31)/32, HD, 0, stream>>>(feats, W1, bias1, h, NN0);
  // agg1 = norm-scatter(h) over b0              -> hb
  agg_kernel<<<(NN1+3)/4, 256, 0, stream>>>(h, off0, lst0, so0, ri0, hb, NN1);
  // conv1 = relu(agg1 @ Wc + bc), in-place      [50000,256]@[256,256]
  gemm_tpc<HD, HD, true, true, true><<<(NN1+31)/32, HD, 0, stream>>>(hb, Wc, bc, hb, NN1);
  // LayerNorm in-place
  ln_kernel<<<(NN1+3)/4, 256, 0, stream>>>(hb, lng, lnb, NN1);
  // agg2 over b1
  agg_kernel<<<(NN2+3)/4, 256, 0, stream>>>(hb, off1, lst1, so1, ri1, ag2, NN2);
  // conv2 = agg2 @ Wo + bo                      [10000,256]@[256,128]
  gemm_tpc<OUT_D, HD, false, true, false><<<(NN2+31)/32, OUT_D, 0, stream>>>(ag2, Wo, bo, c2, NN2);
  // row L2 normalize -> d_out (fp32)
  rownorm_kernel<<<(NN2+3)/4, 256, 0, stream>>>(c2, (float*)d_out, NN2);
}

// Round 2
// 702.021 us; speedup vs baseline: 4.1650x; 4.1650x over previous
//
#include <hip/hip_runtime.h>
#include <hip/hip_bf16.h>

#define NN0 200000
#define NN1 50000
#define NN2 10000
#define IN_DIM 512
#define HD 256
#define OUT_D 128

typedef unsigned short u16;
typedef unsigned int u32;
typedef __attribute__((ext_vector_type(8))) short s16x8;
typedef __attribute__((ext_vector_type(4))) float f32x4;

__device__ __forceinline__ float b2f(u16 u){ return __uint_as_float(((u32)u)<<16); }
__device__ __forceinline__ u16 f2b(float f){
  u32 x = __float_as_uint(f);
  u32 r = x + 0x7fffu + ((x>>16)&1u);
  return (u16)(r>>16);
}

// ---- degree counting (int atomics) ----
__global__ void deg_count(const int* __restrict__ src, const int* __restrict__ dst,
                          int E, int* __restrict__ outc, int* __restrict__ inc){
  int i = blockIdx.x*blockDim.x + threadIdx.x;
  if (i < E){
    atomicAdd(&outc[src[i]], 1);
    atomicAdd(&inc[dst[i]], 1);
  }
}

__global__ void mkscale(const int* __restrict__ c, float* __restrict__ o, int n){
  int i = blockIdx.x*blockDim.x + threadIdx.x;
  if (i < n) o[i] = rsqrtf((float)(c[i] > 1 ? c[i] : 1));
}

// ---- exclusive scan (single block, shuffle-based) ----
__global__ __launch_bounds__(1024) void scan_kernel(const int* __restrict__ cnt,
    int* __restrict__ off, int* __restrict__ cur, int n){
  __shared__ int wsum[16];
  int tid = threadIdx.x, lane = tid & 63, wv = tid >> 6;
  int carry = 0;
  for (int base = 0; base < n; base += 1024){
    int i = base + tid;
    int v = (i < n) ? cnt[i] : 0;
    int x = v;
    #pragma unroll
    for (int d = 1; d < 64; d <<= 1){
      int y = __shfl_up(x, d);
      if (lane >= d) x += y;
    }
    if (lane == 63) wsum[wv] = x;
    __syncthreads();
    if (tid == 0){
      int s = carry;
      #pragma unroll
      for (int k = 0; k < 16; ++k){ int t = wsum[k]; wsum[k] = s; s += t; }
      carry = s;
    }
    __syncthreads();
    int excl = wsum[wv] + x - v;
    if (i < n){ off[i] = excl; cur[i] = excl; }
    __syncthreads();
  }
  if (tid == 0) off[n] = carry;
}

__global__ void fill_kernel(const int* __restrict__ src, const int* __restrict__ dst,
                            int E, int* __restrict__ cur, int* __restrict__ lst){
  int i = blockIdx.x*blockDim.x + threadIdx.x;
  if (i < E){
    int d = dst[i];
    int p = atomicAdd(&cur[d], 1);
    lst[p] = src[i];
  }
}

// ---- W [K][N] f32  ->  WT [N][K] bf16 ----
__global__ void wtrans(const float* __restrict__ W, u16* __restrict__ WT, int K, int N){
  int idx = blockIdx.x*256 + threadIdx.x;
  if (idx < N*K){
    int n = idx / K, k = idx - n*K;
    WT[idx] = f2b(W[(size_t)k*N + n]);
  }
}

// ---- MFMA bf16 GEMM: C[M,N] = A[M,K] @ W[K,N] + bias ----
// A: f32 (ABF=false) or bf16; BT: bf16 [N][K] (pre-transposed); C: bf16 or f32.
// 128x128 tile, BK=32, 4 waves (2x2), each wave 64x64 = 4x4 frags of 16x16x32.
// LDS row stride 40 bf16 (80 B): b128 reads/writes hit the 8-cycle bank floor evenly.
template<int K, bool ABF, bool RELU, bool OBF>
__global__ __launch_bounds__(256) void gemm_mfma(const void* __restrict__ Av,
    const u16* __restrict__ BT, const float* __restrict__ bias,
    void* __restrict__ Cv, int M, int N)
{
  constexpr int BM=128, BN=128, BK=32, LDT=40;
  __shared__ u16 As[BM*LDT];
  __shared__ u16 Bs[BN*LDT];
  const int t = threadIdx.x;
  const int lane = t & 63;
  const int wv = t >> 6;
  const int wr = wv >> 1, wc = wv & 1;
  const int r0 = blockIdx.x * BM;
  const int c0 = blockIdx.y * BN;
  const int m15 = lane & 15, kg = lane >> 4;

  f32x4 acc[4][4] = {};

  for (int k0 = 0; k0 < K; k0 += BK){
    // stage A tile [128][32] and B tile [128][32] (BT rows), 8 bf16 per thread-slot
    #pragma unroll
    for (int j = 0; j < 2; ++j){
      int idx = j*256 + t;
      int r = idx >> 2;
      int kk = (idx & 3) * 8;
      int gr = r0 + r;
      s16x8 v = {};
      if (gr < M){
        if (ABF){
          v = *(const s16x8*)((const u16*)Av + (size_t)gr*K + k0 + kk);
        } else {
          const float* ap = (const float*)Av + (size_t)gr*K + k0 + kk;
          float4 x = *(const float4*)ap;
          float4 y = *(const float4*)(ap + 4);
          v[0]=(short)f2b(x.x); v[1]=(short)f2b(x.y); v[2]=(short)f2b(x.z); v[3]=(short)f2b(x.w);
          v[4]=(short)f2b(y.x); v[5]=(short)f2b(y.y); v[6]=(short)f2b(y.z); v[7]=(short)f2b(y.w);
        }
      }
      *(s16x8*)&As[r*LDT + kk] = v;
      s16x8 w = *(const s16x8*)(BT + (size_t)(c0 + r)*K + k0 + kk);
      *(s16x8*)&Bs[r*LDT + kk] = w;
    }
    __syncthreads();
    s16x8 afr[4], bfr[4];
    #pragma unroll
    for (int i = 0; i < 4; ++i)
      afr[i] = *(const s16x8*)&As[(wr*64 + i*16 + m15)*LDT + kg*8];
    #pragma unroll
    for (int i = 0; i < 4; ++i)
      bfr[i] = *(const s16x8*)&Bs[(wc*64 + i*16 + m15)*LDT + kg*8];
    #pragma unroll
    for (int i = 0; i < 4; ++i)
      #pragma unroll
      for (int j = 0; j < 4; ++j)
        acc[i][j] = __builtin_amdgcn_mfma_f32_16x16x32_bf16(afr[i], bfr[j], acc[i][j], 0, 0, 0);
    __syncthreads();
  }

  // epilogue: C row = (lane>>4)*4 + q, col = lane&15 within each 16x16 frag
  #pragma unroll
  for (int j = 0; j < 4; ++j){
    int col = c0 + wc*64 + j*16 + m15;
    float bv = bias[col];
    #pragma unroll
    for (int i = 0; i < 4; ++i){
      int rbase = r0 + wr*64 + i*16 + kg*4;
      #pragma unroll
      for (int q = 0; q < 4; ++q){
        int row = rbase + q;
        if (row < M){
          float v = acc[i][j][q] + bv;
          if (RELU) v = fmaxf(v, 0.f);
          if (OBF) ((u16*)Cv)[(size_t)row*N + col] = f2b(v);
          else     ((float*)Cv)[(size_t)row*N + col] = v;
        }
      }
    }
  }
}

// ---- CSR pull aggregation: out[d] = ri[d] * sum_e so[src_e]*X[src_e], 256-dim bf16 ----
__global__ __launch_bounds__(256) void agg_kernel(const u16* __restrict__ X,
    const int* __restrict__ off, const int* __restrict__ lst,
    const float* __restrict__ so, const float* __restrict__ ri,
    u16* __restrict__ out, int nd)
{
  int lane = threadIdx.x & 63, wv = threadIdx.x >> 6;
  int d = blockIdx.x*4 + wv;
  if (d >= nd) return;
  int e0 = off[d], e1 = off[d+1];
  float a0=0.f, a1=0.f, a2=0.f, a3=0.f;
  for (int e = e0; e < e1; ++e){
    int s = lst[e];
    float sc = so[s];
    ushort4 u = ((const ushort4*)X)[(size_t)s*64 + lane];
    a0 = fmaf(b2f(u.x), sc, a0);
    a1 = fmaf(b2f(u.y), sc, a1);
    a2 = fmaf(b2f(u.z), sc, a2);
    a3 = fmaf(b2f(u.w), sc, a3);
  }
  float r = ri[d];
  ushort4 o;
  o.x = f2b(a0*r); o.y = f2b(a1*r); o.z = f2b(a2*r); o.w = f2b(a3*r);
  ((ushort4*)out)[(size_t)d*64 + lane] = o;
}

// ---- LayerNorm over 256 cols, in-place bf16, one wave per row ----
__global__ __launch_bounds__(256) void ln_kernel(u16* __restrict__ H,
    const float* __restrict__ g, const float* __restrict__ b, int n)
{
  int lane = threadIdx.x & 63, wv = threadIdx.x >> 6;
  int r = blockIdx.x*4 + wv;
  if (r >= n) return;
  ushort4 u = ((const ushort4*)H)[(size_t)r*64 + lane];
  float x0=b2f(u.x), x1=b2f(u.y), x2=b2f(u.z), x3=b2f(u.w);
  float s = x0+x1+x2+x3;
  #pragma unroll
  for (int d=1; d<64; d<<=1) s += __shfl_xor(s, d);
  float mu = s * (1.f/256.f);
  float d0=x0-mu, d1=x1-mu, d2=x2-mu, d3=x3-mu;
  float v = d0*d0 + d1*d1 + d2*d2 + d3*d3;
  #pragma unroll
  for (int d=1; d<64; d<<=1) v += __shfl_xor(v, d);
  float inv = rsqrtf(v*(1.f/256.f) + 1e-5f);
  float4 gv = ((const float4*)g)[lane];
  float4 bv = ((const float4*)b)[lane];
  ushort4 o;
  o.x = f2b(d0*inv*gv.x + bv.x);
  o.y = f2b(d1*inv*gv.y + bv.y);
  o.z = f2b(d2*inv*gv.z + bv.z);
  o.w = f2b(d3*inv*gv.w + bv.w);
  ((ushort4*)H)[(size_t)r*64 + lane] = o;
}

// ---- row L2-normalize, 128 cols, one wave per row ----
__global__ __launch_bounds__(256) void rownorm_kernel(const float* __restrict__ T,
    float* __restrict__ out, int n)
{
  int lane = threadIdx.x & 63, wv = threadIdx.x >> 6;
  int r = blockIdx.x*4 + wv;
  if (r >= n) return;
  float2 x = ((const float2*)T)[(size_t)r*64 + lane];
  float s = x.x*x.x + x.y*x.y;
  #pragma unroll
  for (int d=1; d<64; d<<=1) s += __shfl_xor(s, d);
  float nrm = sqrtf(s);
  float sc = 1.f / fmaxf(nrm, 1e-12f);
  float2 o; o.x = x.x*sc; o.y = x.y*sc;
  ((float2*)out)[(size_t)r*64 + lane] = o;
}

extern "C" void kernel_launch(void* const* d_in, const int* in_sizes, int n_in,
                              void* d_out, int out_size, void* d_ws, size_t ws_size,
                              hipStream_t stream)
{
  const float* feats = (const float*)d_in[0];
  const int*   b0s   = (const int*)d_in[1];
  const int*   b0d   = (const int*)d_in[2];
  const int*   b1s   = (const int*)d_in[3];
  const int*   b1d   = (const int*)d_in[4];
  const float* W1    = (const float*)d_in[5];
  const float* bias1 = (const float*)d_in[6];
  const float* Wc    = (const float*)d_in[7];
  const float* bc    = (const float*)d_in[8];
  const float* lng   = (const float*)d_in[9];
  const float* lnb   = (const float*)d_in[10];
  const float* Wo    = (const float*)d_in[11];
  const float* bo    = (const float*)d_in[12];
  const int E0 = in_sizes[1];
  const int E1 = in_sizes[3];
  (void)n_in; (void)out_size; (void)ws_size;

  char* p = (char*)d_ws;
  auto alloc = [&](size_t bytes)->void*{ void* q = (void*)p; p += (bytes + 255) & ~(size_t)255; return q; };
  u16*   g1   = (u16*)  alloc((size_t)NN0*HD*2);     // GEMM1 out; later reused for conv1 out + LN
  u16*   hb   = (u16*)  alloc((size_t)NN1*HD*2);     // agg1 out
  u16*   ag2  = (u16*)  alloc((size_t)NN2*HD*2);
  float* c2   = (float*)alloc((size_t)NN2*OUT_D*4);
  u16*   W1T  = (u16*)  alloc((size_t)HD*IN_DIM*2);  // [256][512]
  u16*   WcT  = (u16*)  alloc((size_t)HD*HD*2);      // [256][256]
  u16*   WoT  = (u16*)  alloc((size_t)OUT_D*HD*2);   // [128][256]
  char* cnt_begin = p;
  int* outc0 = (int*)alloc((size_t)NN0*4);
  int* inc0  = (int*)alloc((size_t)NN1*4);
  int* outc1 = (int*)alloc((size_t)NN1*4);
  int* inc1  = (int*)alloc((size_t)NN2*4);
  char* cnt_end = p;
  float* so0 = (float*)alloc((size_t)NN0*4);
  float* ri0 = (float*)alloc((size_t)NN1*4);
  float* so1 = (float*)alloc((size_t)NN1*4);
  float* ri1 = (float*)alloc((size_t)NN2*4);
  int* off0  = (int*)alloc((size_t)(NN1+1)*4);
  int* cur0  = (int*)alloc((size_t)NN1*4);
  int* off1  = (int*)alloc((size_t)(NN2+1)*4);
  int* cur1  = (int*)alloc((size_t)NN2*4);
  int* lst0  = (int*)alloc((size_t)800000*4);
  int* lst1  = (int*)alloc((size_t)160000*4);

  hipMemsetAsync(cnt_begin, 0, (size_t)(cnt_end - cnt_begin), stream);

  // graph prep
  deg_count<<<(E0+255)/256, 256, 0, stream>>>(b0s, b0d, E0, outc0, inc0);
  deg_count<<<(E1+255)/256, 256, 0, stream>>>(b1s, b1d, E1, outc1, inc1);
  mkscale<<<(NN0+255)/256, 256, 0, stream>>>(outc0, so0, NN0);
  mkscale<<<(NN1+255)/256, 256, 0, stream>>>(inc0,  ri0, NN1);
  mkscale<<<(NN1+255)/256, 256, 0, stream>>>(outc1, so1, NN1);
  mkscale<<<(NN2+255)/256, 256, 0, stream>>>(inc1,  ri1, NN2);
  scan_kernel<<<1, 1024, 0, stream>>>(inc0, off0, cur0, NN1);
  scan_kernel<<<1, 1024, 0, stream>>>(inc1, off1, cur1, NN2);
  fill_kernel<<<(E0+255)/256, 256, 0, stream>>>(b0s, b0d, E0, cur0, lst0);
  fill_kernel<<<(E1+255)/256, 256, 0, stream>>>(b1s, b1d, E1, cur1, lst1);

  // weight transposes (tiny)
  wtrans<<<(HD*IN_DIM+255)/256, 256, 0, stream>>>(W1, W1T, IN_DIM, HD);
  wtrans<<<(HD*HD+255)/256, 256, 0, stream>>>(Wc, WcT, HD, HD);
  wtrans<<<(OUT_D*HD+255)/256, 256, 0, stream>>>(Wo, WoT, HD, OUT_D);

  // h = feats @ W1 + bias1   [200000,512]@[512,256] -> g1 (bf16)
  {
    dim3 grid((NN0+127)/128, HD/128);
    gemm_mfma<IN_DIM, false, false, true><<<grid, 256, 0, stream>>>(feats, W1T, bias1, g1, NN0, HD);
  }
  // agg1 over b0 -> hb
  agg_kernel<<<(NN1+3)/4, 256, 0, stream>>>(g1, off0, lst0, so0, ri0, hb, NN1);
  // conv1 = relu(agg1 @ Wc + bc)  [50000,256]@[256,256] -> g1 (region reuse; hb intact)
  {
    dim3 grid((NN1+127)/128, HD/128);
    gemm_mfma<HD, true, true, true><<<grid, 256, 0, stream>>>(hb, WcT, bc, g1, NN1, HD);
  }
  // LayerNorm in-place on g1[0:NN1]
  ln_kernel<<<(NN1+3)/4, 256, 0, stream>>>(g1, lng, lnb, NN1);
  // agg2 over b1 -> ag2
  agg_kernel<<<(NN2+3)/4, 256, 0, stream>>>(g1, off1, lst1, so1, ri1, ag2, NN2);
  // conv2 = agg2 @ Wo + bo  [10000,256]@[256,128] -> c2 (f32)
  {
    dim3 grid((NN2+127)/128, OUT_D/128);
    gemm_mfma<HD, true, false, false><<<grid, 256, 0, stream>>>(ag2, WoT, bo, c2, NN2, OUT_D);
  }
  // row L2 normalize -> d_out (f32)
  rownorm_kernel<<<(NN2+3)/4, 256, 0, stream>>>(c2, (float*)d_out, NN2);
}

// Round 3
// 654.036 us; speedup vs baseline: 4.4705x; 1.0734x over previous
//
#include <hip/hip_runtime.h>
#include <hip/hip_bf16.h>

#define NN0 200000
#define NN1 50000
#define NN2 10000
#define IN_DIM 512
#define HD 256
#define OUT_D 128

typedef unsigned short u16;
typedef unsigned int u32;
typedef __attribute__((ext_vector_type(8))) short s16x8;
typedef __attribute__((ext_vector_type(4))) float f32x4;

__device__ __forceinline__ float b2f(u16 u){ return __uint_as_float(((u32)u)<<16); }
__device__ __forceinline__ u16 f2b(float f){
  u32 x = __float_as_uint(f);
  u32 r = x + 0x7fffu + ((x>>16)&1u);
  return (u16)(r>>16);
}

// ---- degree counting (int atomics) ----
__global__ void deg_count(const int* __restrict__ src, const int* __restrict__ dst,
                          int E, int* __restrict__ outc, int* __restrict__ inc){
  int i = blockIdx.x*blockDim.x + threadIdx.x;
  if (i < E){
    atomicAdd(&outc[src[i]], 1);
    atomicAdd(&inc[dst[i]], 1);
  }
}

__global__ void mkscale(const int* __restrict__ c, float* __restrict__ o, int n){
  int i = blockIdx.x*blockDim.x + threadIdx.x;
  if (i < n) o[i] = rsqrtf((float)(c[i] > 1 ? c[i] : 1));
}

// ---- exclusive scan (single block, shuffle-based) ----
__global__ __launch_bounds__(1024) void scan_kernel(const int* __restrict__ cnt,
    int* __restrict__ off, int* __restrict__ cur, int n){
  __shared__ int wsum[16];
  int tid = threadIdx.x, lane = tid & 63, wv = tid >> 6;
  int carry = 0;
  for (int base = 0; base < n; base += 1024){
    int i = base + tid;
    int v = (i < n) ? cnt[i] : 0;
    int x = v;
    #pragma unroll
    for (int d = 1; d < 64; d <<= 1){
      int y = __shfl_up(x, d);
      if (lane >= d) x += y;
    }
    if (lane == 63) wsum[wv] = x;
    __syncthreads();
    if (tid == 0){
      int s = carry;
      #pragma unroll
      for (int k = 0; k < 16; ++k){ int t = wsum[k]; wsum[k] = s; s += t; }
      carry = s;
    }
    __syncthreads();
    int excl = wsum[wv] + x - v;
    if (i < n){ off[i] = excl; cur[i] = excl; }
    __syncthreads();
  }
  if (tid == 0) off[n] = carry;
}

__global__ void fill_kernel(const int* __restrict__ src, const int* __restrict__ dst,
                            int E, int* __restrict__ cur, int* __restrict__ lst){
  int i = blockIdx.x*blockDim.x + threadIdx.x;
  if (i < E){
    int d = dst[i];
    int p = atomicAdd(&cur[d], 1);
    lst[p] = src[i];
  }
}

// ---- pack W [K][N] f32 into MFMA-B fragment-linear bf16 ----
// chunk c = ((s*(N/16) + f)*64 + lane): 8 bf16 = B[col=f*16+(lane&15)][k=s*32+(lane>>4)*8 ..+8]
__global__ void wpack(const float* __restrict__ W, u16* __restrict__ out, int K, int N){
  int c = blockIdx.x*256 + threadIdx.x;
  int total = (K>>5)*(N>>4)*64;
  if (c >= total) return;
  int lane = c & 63;
  int f = (c >> 6) % (N>>4);
  int s = (c >> 6) / (N>>4);
  int col = f*16 + (lane & 15);
  int k0 = s*32 + (lane >> 4)*8;
  u16* o = out + (size_t)c*8;
  #pragma unroll
  for (int e = 0; e < 8; ++e) o[e] = f2b(W[(size_t)(k0+e)*N + col]);
}

// ---- MFMA bf16 GEMM: C[M,N] = A[M,K] @ W[K,N] + bias ----
// A: f32 (ABF=false) or bf16 row-major. BPK: fragment-packed bf16 (wpack). C: bf16 or f32.
// 128x128 tile, BK=64, A double-buffered in LDS w/ register prefetch; B direct from L2.
template<int K, int N, bool ABF, bool RELU, bool OBF>
__global__ __launch_bounds__(256) void gemm_mfma(const void* __restrict__ Av,
    const u16* __restrict__ BPK, const float* __restrict__ bias,
    void* __restrict__ Cv, int M)
{
  constexpr int BM=128, BK=64, LDT=72, NT=K/BK, NF=N/16;
  __shared__ u16 smem[2*BM*LDT];           // 36864 B; epilogue repack aliases (needs 34816 B)
  const int t = threadIdx.x;
  const int lane = t & 63;
  const int wv = t >> 6;
  const int wr = wv >> 1, wc = wv & 1;
  const int r0 = blockIdx.x * BM;
  const int c0 = blockIdx.y * 128;
  const int m15 = lane & 15, kg = lane >> 4;
  const int fb = (c0 >> 4) + wc*4;

  // staging coords: thread t handles row sr, k-half sh (32 elems = 64B bf16 / 128B f32)
  const int sr = t >> 1, sh = t & 1;
  const int gr = r0 + sr;
  const bool arow = (gr < M);

  float4 pf[8];       // f32 prefetch regs
  s16x8  pb[4];       // bf16 prefetch regs

  auto loadA = [&](int ti){
    if (ABF){
      const u16* ap = (const u16*)Av + (size_t)gr*K + ti*BK + sh*32;
      #pragma unroll
      for (int c = 0; c < 4; ++c)
        pb[c] = arow ? *(const s16x8*)(ap + c*8) : (s16x8){};
    } else {
      const float* ap = (const float*)Av + (size_t)gr*K + ti*BK + sh*32;
      #pragma unroll
      for (int c = 0; c < 8; ++c)
        pf[c] = arow ? *(const float4*)(ap + c*4) : (float4){0.f,0.f,0.f,0.f};
    }
  };
  auto writeA = [&](int buf){
    u16* dst = &smem[buf*BM*LDT + sr*LDT + sh*32];
    if (ABF){
      #pragma unroll
      for (int c = 0; c < 4; ++c) *(s16x8*)(dst + c*8) = pb[c];
    } else {
      #pragma unroll
      for (int c = 0; c < 4; ++c){
        float4 x = pf[2*c], y = pf[2*c+1];
        s16x8 v;
        v[0]=(short)f2b(x.x); v[1]=(short)f2b(x.y); v[2]=(short)f2b(x.z); v[3]=(short)f2b(x.w);
        v[4]=(short)f2b(y.x); v[5]=(short)f2b(y.y); v[6]=(short)f2b(y.z); v[7]=(short)f2b(y.w);
        *(s16x8*)(dst + c*8) = v;
      }
    }
  };

  f32x4 acc[4][4] = {};

  loadA(0);
  writeA(0);

  for (int ti = 0; ti < NT; ++ti){
    if (ti + 1 < NT) loadA(ti + 1);
    // B fragments for this K-tile (two k-steps of 32), direct from L2, fully coalesced
    s16x8 bfr[2][4];
    #pragma unroll
    for (int kh = 0; kh < 2; ++kh)
      #pragma unroll
      for (int j = 0; j < 4; ++j)
        bfr[kh][j] = *(const s16x8*)(BPK + (((size_t)(2*ti+kh)*NF + fb + j)*64 + lane)*8);

    __syncthreads();   // writes to buf[ti&1] visible
    const u16* as = &smem[(ti&1)*BM*LDT];
    s16x8 afr[2][4];
    #pragma unroll
    for (int kh = 0; kh < 2; ++kh)
      #pragma unroll
      for (int i = 0; i < 4; ++i)
        afr[kh][i] = *(const s16x8*)&as[(wr*64 + i*16 + m15)*LDT + kh*32 + kg*8];
    #pragma unroll
    for (int kh = 0; kh < 2; ++kh)
      #pragma unroll
      for (int i = 0; i < 4; ++i)
        #pragma unroll
        for (int j = 0; j < 4; ++j)
          acc[i][j] = __builtin_amdgcn_mfma_f32_16x16x32_bf16(afr[kh][i], bfr[kh][j], acc[i][j], 0, 0, 0);
    __syncthreads();   // reads of buf[ti&1] done
    if (ti + 1 < NT) writeA((ti+1)&1);
  }

  if (OBF){
    // repack epilogue: acc -> LDS (u16 [128][136], 16B-aligned rows) -> coalesced stores
    u16* cs = smem;
    #pragma unroll
    for (int j = 0; j < 4; ++j){
      int colg = c0 + wc*64 + j*16 + m15;
      float bv = bias[colg];
      #pragma unroll
      for (int i = 0; i < 4; ++i){
        int rl = wr*64 + i*16 + kg*4;
        #pragma unroll
        for (int q = 0; q < 4; ++q){
          float v = acc[i][j][q] + bv;
          if (RELU) v = fmaxf(v, 0.f);
          cs[(rl+q)*136 + wc*64 + j*16 + m15] = f2b(v);
        }
      }
    }
    __syncthreads();
    int rr = t >> 1, hh = t & 1;
    int go = r0 + rr;
    if (go < M){
      u16* dst = (u16*)Cv + (size_t)go*N + c0 + hh*64;
      const u16* sp = &cs[rr*136 + hh*64];
      #pragma unroll
      for (int c = 0; c < 8; ++c) *(s16x8*)(dst + c*8) = *(const s16x8*)(sp + c*8);
    }
  } else {
    #pragma unroll
    for (int j = 0; j < 4; ++j){
      int colg = c0 + wc*64 + j*16 + m15;
      float bv = bias[colg];
      #pragma unroll
      for (int i = 0; i < 4; ++i){
        int rbase = r0 + wr*64 + i*16 + kg*4;
        #pragma unroll
        for (int q = 0; q < 4; ++q){
          int row = rbase + q;
          if (row < M){
            float v = acc[i][j][q] + bv;
            if (RELU) v = fmaxf(v, 0.f);
            ((float*)Cv)[(size_t)row*N + colg] = v;
          }
        }
      }
    }
  }
}

// ---- CSR pull aggregation: out[d] = ri[d] * sum_e so[src_e]*X[src_e], 256-dim bf16 ----
__global__ __launch_bounds__(256) void agg_kernel(const u16* __restrict__ X,
    const int* __restrict__ off, const int* __restrict__ lst,
    const float* __restrict__ so, const float* __restrict__ ri,
    u16* __restrict__ out, int nd)
{
  int lane = threadIdx.x & 63, wv = threadIdx.x >> 6;
  int d = blockIdx.x*4 + wv;
  if (d >= nd) return;
  int e0 = off[d], e1 = off[d+1];
  float a0=0.f, a1=0.f, a2=0.f, a3=0.f;
  for (int e = e0; e < e1; ++e){
    int s = lst[e];
    float sc = so[s];
    ushort4 u = ((const ushort4*)X)[(size_t)s*64 + lane];
    a0 = fmaf(b2f(u.x), sc, a0);
    a1 = fmaf(b2f(u.y), sc, a1);
    a2 = fmaf(b2f(u.z), sc, a2);
    a3 = fmaf(b2f(u.w), sc, a3);
  }
  float r = ri[d];
  ushort4 o;
  o.x = f2b(a0*r); o.y = f2b(a1*r); o.z = f2b(a2*r); o.w = f2b(a3*r);
  ((ushort4*)out)[(size_t)d*64 + lane] = o;
}

// ---- LayerNorm over 256 cols, in-place bf16, one wave per row ----
__global__ __launch_bounds__(256) void ln_kernel(u16* __restrict__ H,
    const float* __restrict__ g, const float* __restrict__ b, int n)
{
  int lane = threadIdx.x & 63, wv = threadIdx.x >> 6;
  int r = blockIdx.x*4 + wv;
  if (r >= n) return;
  ushort4 u = ((const ushort4*)H)[(size_t)r*64 + lane];
  float x0=b2f(u.x), x1=b2f(u.y), x2=b2f(u.z), x3=b2f(u.w);
  float s = x0+x1+x2+x3;
  #pragma unroll
  for (int d=1; d<64; d<<=1) s += __shfl_xor(s, d);
  float mu = s * (1.f/256.f);
  float d0=x0-mu, d1=x1-mu, d2=x2-mu, d3=x3-mu;
  float v = d0*d0 + d1*d1 + d2*d2 + d3*d3;
  #pragma unroll
  for (int d=1; d<64; d<<=1) v += __shfl_xor(v, d);
  float inv = rsqrtf(v*(1.f/256.f) + 1e-5f);
  float4 gv = ((const float4*)g)[lane];
  float4 bv = ((const float4*)b)[lane];
  ushort4 o;
  o.x = f2b(d0*inv*gv.x + bv.x);
  o.y = f2b(d1*inv*gv.y + bv.y);
  o.z = f2b(d2*inv*gv.z + bv.z);
  o.w = f2b(d3*inv*gv.w + bv.w);
  ((ushort4*)H)[(size_t)r*64 + lane] = o;
}

// ---- row L2-normalize, 128 cols, one wave per row ----
__global__ __launch_bounds__(256) void rownorm_kernel(const float* __restrict__ T,
    float* __restrict__ out, int n)
{
  int lane = threadIdx.x & 63, wv = threadIdx.x >> 6;
  int r = blockIdx.x*4 + wv;
  if (r >= n) return;
  float2 x = ((const float2*)T)[(size_t)r*64 + lane];
  float s = x.x*x.x + x.y*x.y;
  #pragma unroll
  for (int d=1; d<64; d<<=1) s += __shfl_xor(s, d);
  float nrm = sqrtf(s);
  float sc = 1.f / fmaxf(nrm, 1e-12f);
  float2 o; o.x = x.x*sc; o.y = x.y*sc;
  ((float2*)out)[(size_t)r*64 + lane] = o;
}

extern "C" void kernel_launch(void* const* d_in, const int* in_sizes, int n_in,
                              void* d_out, int out_size, void* d_ws, size_t ws_size,
                              hipStream_t stream)
{
  const float* feats = (const float*)d_in[0];
  const int*   b0s   = (const int*)d_in[1];
  const int*   b0d   = (const int*)d_in[2];
  const int*   b1s   = (const int*)d_in[3];
  const int*   b1d   = (const int*)d_in[4];
  const float* W1    = (const float*)d_in[5];
  const float* bias1 = (const float*)d_in[6];
  const float* Wc    = (const float*)d_in[7];
  const float* bc    = (const float*)d_in[8];
  const float* lng   = (const float*)d_in[9];
  const float* lnb   = (const float*)d_in[10];
  const float* Wo    = (const float*)d_in[11];
  const float* bo    = (const float*)d_in[12];
  const int E0 = in_sizes[1];
  const int E1 = in_sizes[3];
  (void)n_in; (void)out_size; (void)ws_size;

  char* p = (char*)d_ws;
  auto alloc = [&](size_t bytes)->void*{ void* q = (void*)p; p += (bytes + 255) & ~(size_t)255; return q; };
  u16*   g1   = (u16*)  alloc((size_t)NN0*HD*2);     // GEMM1 out; reused for conv1 out + LN
  u16*   hb   = (u16*)  alloc((size_t)NN1*HD*2);     // agg1 out
  u16*   ag2  = (u16*)  alloc((size_t)NN2*HD*2);
  float* c2   = (float*)alloc((size_t)NN2*OUT_D*4);
  u16*   W1P  = (u16*)  alloc((size_t)HD*IN_DIM*2);
  u16*   WcP  = (u16*)  alloc((size_t)HD*HD*2);
  u16*   WoP  = (u16*)  alloc((size_t)OUT_D*HD*2);
  char* cnt_begin = p;
  int* outc0 = (int*)alloc((size_t)NN0*4);
  int* inc0  = (int*)alloc((size_t)NN1*4);
  int* outc1 = (int*)alloc((size_t)NN1*4);
  int* inc1  = (int*)alloc((size_t)NN2*4);
  char* cnt_end = p;
  float* so0 = (float*)alloc((size_t)NN0*4);
  float* ri0 = (float*)alloc((size_t)NN1*4);
  float* so1 = (float*)alloc((size_t)NN1*4);
  float* ri1 = (float*)alloc((size_t)NN2*4);
  int* off0  = (int*)alloc((size_t)(NN1+1)*4);
  int* cur0  = (int*)alloc((size_t)NN1*4);
  int* off1  = (int*)alloc((size_t)(NN2+1)*4);
  int* cur1  = (int*)alloc((size_t)NN2*4);
  int* lst0  = (int*)alloc((size_t)800000*4);
  int* lst1  = (int*)alloc((size_t)160000*4);

  hipMemsetAsync(cnt_begin, 0, (size_t)(cnt_end - cnt_begin), stream);

  // graph prep
  deg_count<<<(E0+255)/256, 256, 0, stream>>>(b0s, b0d, E0, outc0, inc0);
  deg_count<<<(E1+255)/256, 256, 0, stream>>>(b1s, b1d, E1, outc1, inc1);
  mkscale<<<(NN0+255)/256, 256, 0, stream>>>(outc0, so0, NN0);
  mkscale<<<(NN1+255)/256, 256, 0, stream>>>(inc0,  ri0, NN1);
  mkscale<<<(NN1+255)/256, 256, 0, stream>>>(outc1, so1, NN1);
  mkscale<<<(NN2+255)/256, 256, 0, stream>>>(inc1,  ri1, NN2);
  scan_kernel<<<1, 1024, 0, stream>>>(inc0, off0, cur0, NN1);
  scan_kernel<<<1, 1024, 0, stream>>>(inc1, off1, cur1, NN2);
  fill_kernel<<<(E0+255)/256, 256, 0, stream>>>(b0s, b0d, E0, cur0, lst0);
  fill_kernel<<<(E1+255)/256, 256, 0, stream>>>(b1s, b1d, E1, cur1, lst1);

  // weight fragment-packing (tiny)
  wpack<<<((IN_DIM/32)*(HD/16)*64 + 255)/256, 256, 0, stream>>>(W1, W1P, IN_DIM, HD);
  wpack<<<((HD/32)*(HD/16)*64 + 255)/256, 256, 0, stream>>>(Wc, WcP, HD, HD);
  wpack<<<((HD/32)*(OUT_D/16)*64 + 255)/256, 256, 0, stream>>>(Wo, WoP, HD, OUT_D);

  // h = feats @ W1 + bias1   [200000,512]@[512,256] -> g1 (bf16)
  {
    dim3 grid((NN0+127)/128, HD/128);
    gemm_mfma<IN_DIM, HD, false, false, true><<<grid, 256, 0, stream>>>(feats, W1P, bias1, g1, NN0);
  }
  // agg1 over b0 -> hb
  agg_kernel<<<(NN1+3)/4, 256, 0, stream>>>(g1, off0, lst0, so0, ri0, hb, NN1);
  // conv1 = relu(agg1 @ Wc + bc)  [50000,256]@[256,256] -> g1 (region reuse; hb intact)
  {
    dim3 grid((NN1+127)/128, HD/128);
    gemm_mfma<HD, HD, true, true, true><<<grid, 256, 0, stream>>>(hb, WcP, bc, g1, NN1);
  }
  // LayerNorm in-place on g1[0:NN1]
  ln_kernel<<<(NN1+3)/4, 256, 0, stream>>>(g1, lng, lnb, NN1);
  // agg2 over b1 -> ag2
  agg_kernel<<<(NN2+3)/4, 256, 0, stream>>>(g1, off1, lst1, so1, ri1, ag2, NN2);
  // conv2 = agg2 @ Wo + bo  [10000,256]@[256,128] -> c2 (f32)
  {
    dim3 grid((NN2+127)/128, OUT_D/128);
    gemm_mfma<HD, OUT_D, true, false, false><<<grid, 256, 0, stream>>>(ag2, WoP, bo, c2, NN2);
  }
  // row L2 normalize -> d_out (f32)
  rownorm_kernel<<<(NN2+3)/4, 256, 0, stream>>>(c2, (float*)d_out, NN2);
}